// Round 8
// baseline (713.407 us; speedup 1.0000x reference)
//
#include <hip/hip_runtime.h>

// Problem constants
#define NPOS   524288         // 8*16*64*64
#define KCODES 512
#define CDIM   64
#define THW    65536          // 16*64*64
#define MPOS   256            // positions per block
#define NTHR   256            // 4 waves; one position per thread
#define QB     16             // codes per pass
#define NPASS  32             // 512 / QB

// out layout (float32): [0, 33554432) quantized BCTHW; [33554432] loss; [33554433, +524288) indices
#define QOUT_N   33554432L
#define LOSS_OFF 33554432L
#define IDX_OFF  33554433L

// ws layout: byte 0: double loss acc; byte 256: float ee[512]; byte 4096: float etg[32][64][16]
//   etg[ps][c][k] = emb[ps*16+k][c]

// ---------- prep: ee[q] (numpy pairwise-8) and pass-grouped transposed codebook ----------
extern "C" __global__ void vq_prep(const float* __restrict__ emb,
                                   float* __restrict__ ee, float* __restrict__ etg) {
    int q = threadIdx.x;               // 512 threads
    const float* er = emb + q * 64;
    float r[8];
    #pragma unroll
    for (int j = 0; j < 8; ++j) { float v = er[j]; r[j] = __fmul_rn(v, v); }
    #pragma unroll
    for (int t = 1; t < 8; ++t)
        #pragma unroll
        for (int j = 0; j < 8; ++j) { float v = er[t * 8 + j]; r[j] = __fadd_rn(r[j], __fmul_rn(v, v)); }
    float s0 = __fadd_rn(__fadd_rn(r[0], r[1]), __fadd_rn(r[2], r[3]));
    float s1 = __fadd_rn(__fadd_rn(r[4], r[5]), __fadd_rn(r[6], r[7]));
    ee[q] = __fadd_rn(s0, s1);
    int ps = q >> 4, k = q & 15;
    #pragma unroll
    for (int c = 0; c < 64; ++c) etg[(ps * 64 + c) * QB + k] = er[c];
}

// ---------- main: A in LDS [c][256], E via scalar path, 1 position/thread ----------
extern "C" __global__ __launch_bounds__(NTHR, 2)
void vq_main(const float* __restrict__ x, const float* __restrict__ emb,
             float* __restrict__ out, double* __restrict__ lossws,
             const float* __restrict__ eeg, const float* __restrict__ etg) {
    extern __shared__ float a[];       // [64][256], a[c*256 + p]
    const int tid = threadIdx.x;
    const int blk = blockIdx.x;
    const int b   = blk >> 8;                    // 256 blocks per batch element
    const int r0  = (blk & 255) << 8;            // position base within THW
    const long n  = (long)blk * MPOS + tid;      // global position index

    // ---- stage A-tile [64][256] via global_load_lds (16B), linear dest (proven R2-R4)
    const float* xb = x + (long)b * CDIM * THW + r0;
    #pragma unroll
    for (int k = 0; k < 16; ++k) {
        int g = tid + NTHR * k;                  // float4-unit index 0..4095
        int c = g >> 6, p4 = g & 63;
        __builtin_amdgcn_global_load_lds(
            (const __attribute__((address_space(1))) void*)(xb + (long)c * THW + p4 * 4),
            (__attribute__((address_space(3))) void*)(a + g * 4), 16, 0, 0);
    }
    __syncthreads();   // drains vmcnt; A ready

    // ---- ff = sum_c a^2, numpy pairwise-8 (thread's own column; proven R4 code)
    float ffv;
    {
        float rr[8];
        #pragma unroll
        for (int j = 0; j < 8; ++j) { float v = a[j * 256 + tid]; rr[j] = __fmul_rn(v, v); }
        #pragma unroll
        for (int t = 1; t < 8; ++t)
            #pragma unroll
            for (int j = 0; j < 8; ++j) {
                float v = a[(t * 8 + j) * 256 + tid];
                rr[j] = __fadd_rn(rr[j], __fmul_rn(v, v));
            }
        float s0 = __fadd_rn(__fadd_rn(rr[0], rr[1]), __fadd_rn(rr[2], rr[3]));
        float s1 = __fadd_rn(__fadd_rn(rr[4], rr[5]), __fadd_rn(rr[6], rr[7]));
        ffv = __fadd_rn(s0, s1);
    }

    // ---- argmin: 32 passes of 16 codes; e/ee via uniform s_loads; A re-read from LDS
    float dmin = 1e30f; int kmin = 0;
    #pragma unroll 1
    for (int ps = 0; ps < NPASS; ++ps) {
        const float* eq  = etg + ps * (64 * QB);   // uniform -> s_load (base + imm)
        const float* ees = eeg + ps * QB;          // uniform -> s_load
        float acc[QB];
        // c = 0: chain starts with multiply (bit-safe vs fma-into-zero: only
        // sign-of-zero can differ, which cannot change a strict-< argmin)
        {
            float av = a[tid];
            #pragma unroll
            for (int k = 0; k < QB; ++k) acc[k] = __fmul_rn(av, eq[k]);
        }
        #pragma unroll
        for (int c = 1; c < 64; ++c) {
            float av = a[c * 256 + tid];           // ds_read_b32, imm offset c*1024
            const float* er = eq + c * QB;
            #pragma unroll
            for (int k = 0; k < QB; ++k) acc[k] = __fmaf_rn(av, er[k], acc[k]);
        }
        // distances, q ascending, strict <   (d == (ff+ee) - fl(2*acc) bit-exact)
        #pragma unroll
        for (int k = 0; k < QB; ++k) {
            float t1 = __fadd_rn(ffv, ees[k]);
            float d  = __fmaf_rn(acc[k], -2.0f, t1);
            int q = ps * QB + k;
            if (d < dmin) { dmin = d; kmin = q; }
        }
    }

    // ---- indices out (as float)
    out[IDX_OFF + n] = (float)kmin;

    // ---- quantized out (straight-through) + loss partial (proven R5-7 epilogue,
    //      x re-read from LDS column instead of registers)
    double lacc = 0.0;
    {
        const float* eqr = emb + (long)kmin * 64;  // divergent, L2-hot, 16B-aligned
        float* op = out + (long)b * CDIM * THW + r0 + tid;
        #pragma unroll
        for (int c4 = 0; c4 < 16; ++c4) {
            float4 ev = *(const float4*)(eqr + c4 * 4);
            float x0 = a[(c4 * 4 + 0) * 256 + tid], d0 = __fsub_rn(ev.x, x0);
            op[(long)(c4 * 4 + 0) * THW] = __fadd_rn(x0, d0); lacc += (double)__fmul_rn(d0, d0);
            float x1 = a[(c4 * 4 + 1) * 256 + tid], d1 = __fsub_rn(ev.y, x1);
            op[(long)(c4 * 4 + 1) * THW] = __fadd_rn(x1, d1); lacc += (double)__fmul_rn(d1, d1);
            float x2 = a[(c4 * 4 + 2) * 256 + tid], d2 = __fsub_rn(ev.z, x2);
            op[(long)(c4 * 4 + 2) * THW] = __fadd_rn(x2, d2); lacc += (double)__fmul_rn(d2, d2);
            float x3 = a[(c4 * 4 + 3) * 256 + tid], d3 = __fsub_rn(ev.w, x3);
            op[(long)(c4 * 4 + 3) * THW] = __fadd_rn(x3, d3); lacc += (double)__fmul_rn(d3, d3);
        }
    }

    // ---- loss: wave reduce, then 4-wave LDS reduce, one atomic per block
    #pragma unroll
    for (int m = 1; m < 64; m <<= 1) lacc += __shfl_xor(lacc, m, 64);
    __shared__ double wsum[4];
    if ((tid & 63) == 0) wsum[tid >> 6] = lacc;
    __syncthreads();
    if (tid == 0) {
        atomicAdd(lossws, wsum[0] + wsum[1] + wsum[2] + wsum[3]);
    }
}

extern "C" __global__ void vq_finalize(const double* __restrict__ lossws,
                                       float* __restrict__ out) {
    if (threadIdx.x == 0) {
        float m = (float)(lossws[0] / (double)QOUT_N);
        out[LOSS_OFF] = __fadd_rn(m, __fmul_rn(0.025f, m));
    }
}

extern "C" void kernel_launch(void* const* d_in, const int* in_sizes, int n_in,
                              void* d_out, int out_size, void* d_ws, size_t ws_size,
                              hipStream_t stream) {
    const float* x   = (const float*)d_in[0];
    const float* emb = (const float*)d_in[1];
    float* out = (float*)d_out;
    double* loss_ws = (double*)d_ws;
    float* ee_ws  = (float*)((char*)d_ws + 256);
    float* etg_ws = (float*)((char*)d_ws + 4096);

    hipMemsetAsync(d_ws, 0, sizeof(double), stream);
    hipLaunchKernelGGL(vq_prep, dim3(1), dim3(KCODES), 0, stream, emb, ee_ws, etg_ws);

    dim3 grid(NPOS / MPOS);   // 2048
    dim3 block(NTHR);
    size_t shmem = 64 * 256 * sizeof(float);  // 65536 B -> 2 blocks/CU
    hipLaunchKernelGGL(vq_main, grid, block, shmem, stream, x, emb, out, loss_ws, ee_ws, etg_ws);
    hipLaunchKernelGGL(vq_finalize, dim3(1), dim3(1), 0, stream,
                       (const double*)loss_ws, out);
}

// Round 9
// 335.033 us; speedup vs baseline: 2.1294x; 2.1294x over previous
//
#include <hip/hip_runtime.h>

typedef float f32x4 __attribute__((ext_vector_type(4)));
typedef __bf16 bf16x8 __attribute__((ext_vector_type(8)));
typedef short s16x8 __attribute__((ext_vector_type(8)));

// Problem constants
#define NPOS   524288         // 8*16*64*64
#define KCODES 512
#define CDIM   64
#define THW    65536          // 16*64*64
#define MPOS   256            // positions per block
#define NTHR   512            // 8 waves
#define NCH    8              // e-chunks of 64 codes
#define EPS2   4e-4f          // 2*epsilon certification threshold

// out layout (float32): [0, 33554432) quantized BCTHW; [33554432] loss; [33554433,+524288) indices
#define QOUT_N   33554432L
#define LOSSOFF  33554432L
#define IDX_OFF  33554433L

// ws: 0: double loss; 256: float eeg[512]; 4096: ushort ehi_g[8][512][8]; 69632: ushort emid_g[8][512][8]

__device__ inline unsigned int bf16_rne(unsigned int xb) {   // RN-even fp32->bf16 (no NaN/inf in data)
    return (xb + 0x7fffu + ((xb >> 16) & 1u)) >> 16;
}

#define GLOAD16(gp, lp) __builtin_amdgcn_global_load_lds( \
    (const __attribute__((address_space(1))) void*)(gp), \
    (__attribute__((address_space(3))) void*)(lp), 16, 0, 0)

__device__ inline f32x4 mf(s16x8 a, s16x8 b, f32x4 c) {
    return __builtin_amdgcn_mfma_f32_16x16x32_bf16(
        __builtin_bit_cast(bf16x8, a), __builtin_bit_cast(bf16x8, b), c, 0, 0, 0);
}

// bit-exact distance key (same chain as passing R4/R6 kernels): (dist_bits<<32)|code
__device__ inline unsigned long long exact_key(const float* a, const float* ffl,
                                               const float* eel, const float* __restrict__ emb,
                                               int pos, int q) {
    const float* er = emb + (long)q * 64;
    float acc = __fmul_rn(a[pos], er[0]);
    #pragma unroll
    for (int c = 1; c < 64; ++c) acc = __fmaf_rn(a[c * 256 + pos], er[c], acc);
    float t1 = __fadd_rn(ffl[pos], eel[q]);
    float d  = __fmaf_rn(acc, -2.0f, t1);
    return ((unsigned long long)__float_as_uint(d) << 32) | (unsigned)q;
}

// ---------- prep: exact ee[q] (numpy pairwise-8) + bf16 hi/mid split codebook ----------
extern "C" __global__ void vq_prep(const float* __restrict__ emb, float* __restrict__ ee,
                                   unsigned short* __restrict__ ehi, unsigned short* __restrict__ emid) {
    int q = threadIdx.x;               // 512 threads
    const float* er = emb + q * 64;
    float r[8];
    #pragma unroll
    for (int j = 0; j < 8; ++j) { float v = er[j]; r[j] = __fmul_rn(v, v); }
    #pragma unroll
    for (int t = 1; t < 8; ++t)
        #pragma unroll
        for (int j = 0; j < 8; ++j) { float v = er[t * 8 + j]; r[j] = __fadd_rn(r[j], __fmul_rn(v, v)); }
    float s0 = __fadd_rn(__fadd_rn(r[0], r[1]), __fadd_rn(r[2], r[3]));
    float s1 = __fadd_rn(__fadd_rn(r[4], r[5]), __fadd_rn(r[6], r[7]));
    ee[q] = __fadd_rn(s0, s1);
    #pragma unroll
    for (int c = 0; c < 64; ++c) {
        float x = er[c];
        unsigned int hb = bf16_rne(__float_as_uint(x));
        float hif = __uint_as_float(hb << 16);
        float m = __fsub_rn(x, hif);                 // exact (Sterbenz)
        unsigned int mb = bf16_rne(__float_as_uint(m));
        long o = ((long)(c >> 3) * 512 + q) * 8 + (c & 7);   // [kg][code][8]
        ehi[o]  = (unsigned short)hb;
        emid[o] = (unsigned short)mb;
    }
}

// ---------- main ----------
extern "C" __global__ __launch_bounds__(NTHR, 1)
void vq_main(const float* __restrict__ x, const float* __restrict__ emb,
             float* __restrict__ out, double* __restrict__ lossws,
             const float* __restrict__ eeg,
             const unsigned short* __restrict__ ehi_g,
             const unsigned short* __restrict__ emid_g) {
    extern __shared__ char smem[];
    float*          a     = (float*)smem;                          // [64][256] fp32  65536 B
    unsigned short* ahi   = (unsigned short*)(smem + 65536);       // [8][256][8]     32768 B
    unsigned short* amid  = (unsigned short*)(smem + 98304);       // [8][256][8]     32768 B
    unsigned short* ehc   = (unsigned short*)(smem + 131072);      // [8][64][8]       8192 B
    unsigned short* emc   = (unsigned short*)(smem + 139264);      // [8][64][8]       8192 B
    float*          eel   = (float*)(smem + 147456);               // [512]            2048 B
    float*          ffl   = (float*)(smem + 149504);               // [256]            1024 B
    int*            kminl = (int*)(smem + 150528);                 // [256]            1024 B
    int*            wl    = (int*)(smem + 151552);                 // [256]            1024 B
    int*            wcnt  = (int*)(smem + 152576);                 //                     8 B
    unsigned long long* wred = (unsigned long long*)(smem + 152584); // [8]              64 B
    double*         wsum  = (double*)(smem + 152648);              // [8]                64 B

    const int tid  = threadIdx.x;
    const int lane = tid & 63;
    const int w    = tid >> 6;                    // wave 0..7 -> positions [w*32, w*32+32)
    const int blk  = blockIdx.x;
    const int b    = blk >> 8;                    // 256 blocks per batch element
    const int r0   = (blk & 255) << 8;
    const long n0  = (long)blk * MPOS;

    if (tid == 0) *wcnt = 0;

    // ---- phase 1: stage x-tile [64][256] + eel + e-chunk 0 (all linear-dest gload_lds)
    const float* xb = x + (long)b * CDIM * THW + r0;
    #pragma unroll
    for (int k = 0; k < 8; ++k) {
        int g = tid + NTHR * k;                   // 16B-unit 0..4095
        int c = g >> 6, p4 = g & 63;
        GLOAD16(xb + (long)c * THW + p4 * 4, a + g * 4);
    }
    if (tid < 128) GLOAD16(eeg + tid * 4, eel + tid * 4);
    {
        int kg = tid >> 6, cc = tid & 63;
        long go = ((long)kg * 512 + cc) * 8;      // chunk 0
        GLOAD16(ehi_g + go, ehc + tid * 8);
        GLOAD16(emid_g + go, emc + tid * 8);
    }
    __syncthreads();

    // ---- phase 2a: ff[p] exact (numpy pairwise-8; proven R2 code)
    if (tid < 256) {
        float rr[8];
        #pragma unroll
        for (int j = 0; j < 8; ++j) { float v = a[j * 256 + tid]; rr[j] = __fmul_rn(v, v); }
        #pragma unroll
        for (int t = 1; t < 8; ++t)
            #pragma unroll
            for (int j = 0; j < 8; ++j) {
                float v = a[(t * 8 + j) * 256 + tid];
                rr[j] = __fadd_rn(rr[j], __fmul_rn(v, v));
            }
        float s0 = __fadd_rn(__fadd_rn(rr[0], rr[1]), __fadd_rn(rr[2], rr[3]));
        float s1 = __fadd_rn(__fadd_rn(rr[4], rr[5]), __fadd_rn(rr[6], rr[7]));
        ffl[tid] = __fadd_rn(s0, s1);
    }
    // ---- phase 2b: split x -> bf16 hi/mid tiles [kg][pos][8]
    {
        int pos = tid & 255, hb2 = tid >> 8;      // hb2: 0/1 -> kg 0-3 / 4-7
        #pragma unroll
        for (int g = 0; g < 4; ++g) {
            int kg = hb2 * 4 + g;
            unsigned short hv[8], mv[8];
            #pragma unroll
            for (int j = 0; j < 8; ++j) {
                float xv = a[(kg * 8 + j) * 256 + pos];
                unsigned int hb = bf16_rne(__float_as_uint(xv));
                float hif = __uint_as_float(hb << 16);
                float m = __fsub_rn(xv, hif);
                unsigned int mb = bf16_rne(__float_as_uint(m));
                hv[j] = (unsigned short)hb; mv[j] = (unsigned short)mb;
            }
            s16x8 hvv, mvv;
            #pragma unroll
            for (int j = 0; j < 8; ++j) { hvv[j] = (short)hv[j]; mvv[j] = (short)mv[j]; }
            *(s16x8*)(ahi  + (kg * 256 + pos) * 8) = hvv;
            *(s16x8*)(amid + (kg * 256 + pos) * 8) = mvv;
        }
    }
    __syncthreads();

    // ---- phase 3: per-wave A-frags (registers, reused all chunks) + ff values
    s16x8 fah[2][2], fam[2][2];
    #pragma unroll
    for (int mt = 0; mt < 2; ++mt)
        #pragma unroll
        for (int ks = 0; ks < 2; ++ks) {
            int kg = ks * 4 + (lane >> 4);
            int pin = w * 32 + mt * 16 + (lane & 15);
            fah[mt][ks] = *(const s16x8*)(ahi  + (kg * 256 + pin) * 8);
            fam[mt][ks] = *(const s16x8*)(amid + (kg * 256 + pin) * 8);
        }
    float ffv[8];
    #pragma unroll
    for (int mt = 0; mt < 2; ++mt)
        #pragma unroll
        for (int rg = 0; rg < 4; ++rg)
            ffv[mt * 4 + rg] = ffl[w * 32 + mt * 16 + (lane >> 4) * 4 + rg];

    unsigned long long u1[8], u2[8];
    #pragma unroll
    for (int s = 0; s < 8; ++s) { u1[s] = ~0ull; u2[s] = ~0ull; }

    // ---- phase 4: MFMA distance scan, 8 chunks x 4 code-tiles
    #pragma unroll 1
    for (int ch = 0; ch < NCH; ++ch) {
        if (ch) {
            __syncthreads();
            int kg = tid >> 6, cc = tid & 63;
            long go = ((long)kg * 512 + (long)ch * 64 + cc) * 8;
            GLOAD16(ehi_g + go, ehc + tid * 8);
            GLOAD16(emid_g + go, emc + tid * 8);
            __syncthreads();
        }
        #pragma unroll
        for (int nt = 0; nt < 4; ++nt) {
            int kg0 = lane >> 4, cin = nt * 16 + (lane & 15);
            s16x8 bh0 = *(const s16x8*)(ehc + ((kg0    ) * 64 + cin) * 8);
            s16x8 bh1 = *(const s16x8*)(ehc + ((kg0 + 4) * 64 + cin) * 8);
            s16x8 bm0 = *(const s16x8*)(emc + ((kg0    ) * 64 + cin) * 8);
            s16x8 bm1 = *(const s16x8*)(emc + ((kg0 + 4) * 64 + cin) * 8);
            unsigned code = ch * 64 + nt * 16 + (lane & 15);
            float eev = eel[code];
            #pragma unroll
            for (int mt = 0; mt < 2; ++mt) {
                f32x4 acc = {0.f, 0.f, 0.f, 0.f};
                acc = mf(fah[mt][0], bh0, acc);
                acc = mf(fah[mt][1], bh1, acc);
                acc = mf(fah[mt][0], bm0, acc);
                acc = mf(fah[mt][1], bm1, acc);
                acc = mf(fam[mt][0], bh0, acc);
                acc = mf(fam[mt][1], bh1, acc);
                #pragma unroll
                for (int rg = 0; rg < 4; ++rg) {
                    int s = mt * 4 + rg;
                    float t1 = __fadd_rn(ffv[s], eev);
                    float d  = __fmaf_rn(acc[rg], -2.0f, t1);
                    unsigned long long key = ((unsigned long long)__float_as_uint(d) << 32) | code;
                    bool c1 = key < u1[s];
                    unsigned long long nu2 = key < u2[s] ? key : u2[s];
                    u2[s] = c1 ? u1[s] : nu2;
                    u1[s] = c1 ? key : u1[s];
                }
            }
        }
    }

    // ---- phase 5: cross-lane top-3 merge (within 16 code-lanes) + certify
    #pragma unroll
    for (int s = 0; s < 8; ++s) {
        unsigned long long v1 = u1[s], v2 = u2[s];
        #pragma unroll
        for (int m = 1; m <= 8; m <<= 1) {
            unsigned long long p1 = __shfl_xor(v1, m, 64);
            unsigned long long p2 = __shfl_xor(v2, m, 64);
            unsigned long long lo  = v1 < p1 ? v1 : p1;
            unsigned long long hi  = v1 < p1 ? p1 : v1;
            unsigned long long mn2 = v2 < p2 ? v2 : p2;
            v1 = lo;
            v2 = hi < mn2 ? hi : mn2;
        }
        // union 3rd-smallest via exclusion (keys unique: code field)
        unsigned long long ex = (u1[s] != v1 && u1[s] != v2) ? u1[s]
                              : ((u2[s] != v1 && u2[s] != v2) ? u2[s] : ~0ull);
        #pragma unroll
        for (int m = 1; m <= 8; m <<= 1) {
            unsigned long long p = __shfl_xor(ex, m, 64);
            ex = p < ex ? p : ex;
        }
        if ((lane & 15) == 0) {
            int pos = w * 32 + (s >> 2) * 16 + (lane >> 4) * 4 + (s & 3);
            float d1 = __uint_as_float((unsigned)(v1 >> 32));
            float d2 = __uint_as_float((unsigned)(v2 >> 32));
            float d3 = __uint_as_float((unsigned)(ex >> 32));
            float thr = __fadd_rn(d1, EPS2);
            if (d2 > thr) {
                kminl[pos] = (int)(v1 & 0xffffffffu);                    // certified fast
            } else if (d3 > thr) {                                      // candidates == {k1,k2}
                unsigned long long ka = exact_key(a, ffl, eel, emb, pos, (int)(v1 & 0xffffffffu));
                unsigned long long kb = exact_key(a, ffl, eel, emb, pos, (int)(v2 & 0xffffffffu));
                unsigned long long km = ka < kb ? ka : kb;
                kminl[pos] = (int)(km & 0xffffffffu);
            } else {
                wl[atomicAdd(wcnt, 1)] = pos;                           // rare: full exact scan
            }
        }
    }
    __syncthreads();

    // ---- phase 6: slow path — block-cooperative exact scan (512 threads = 512 codes)
    int nw = *wcnt;
    for (int i = 0; i < nw; ++i) {
        int pos = wl[i];
        unsigned long long key = exact_key(a, ffl, eel, emb, pos, tid);
        #pragma unroll
        for (int m = 1; m < 64; m <<= 1) {
            unsigned long long p = __shfl_xor(key, m, 64);
            key = p < key ? p : key;
        }
        if (lane == 0) wred[w] = key;
        __syncthreads();
        if (tid == 0) {
            unsigned long long km = wred[0];
            #pragma unroll
            for (int j = 1; j < 8; ++j) km = wred[j] < km ? wred[j] : km;
            kminl[pos] = (int)(km & 0xffffffffu);
        }
        __syncthreads();
    }

    // ---- indices out (as float)
    if (tid < 256) out[IDX_OFF + n0 + tid] = (float)kminl[tid];

    // ---- quantized out (straight-through) + loss partial (proven R4 epilogue)
    double lacc = 0.0;
    {
        const int col = (tid & 63) * 4;
        int iv[4];
        #pragma unroll
        for (int jj = 0; jj < 4; ++jj) iv[jj] = kminl[col + jj];
        float* ob = out + (long)b * CDIM * THW + r0;
        #pragma unroll
        for (int k = 0; k < 8; ++k) {
            int c = (tid >> 6) + 8 * k;
            float4 xv = *(const float4*)(a + c * 256 + col);
            float4 ov;
            float q0 = emb[iv[0] * 64 + c];
            float d0 = __fsub_rn(q0, xv.x); ov.x = __fadd_rn(xv.x, d0); lacc += (double)__fmul_rn(d0, d0);
            float q1 = emb[iv[1] * 64 + c];
            float d1 = __fsub_rn(q1, xv.y); ov.y = __fadd_rn(xv.y, d1); lacc += (double)__fmul_rn(d1, d1);
            float q2 = emb[iv[2] * 64 + c];
            float d2 = __fsub_rn(q2, xv.z); ov.z = __fadd_rn(xv.z, d2); lacc += (double)__fmul_rn(d2, d2);
            float q3 = emb[iv[3] * 64 + c];
            float d3 = __fsub_rn(q3, xv.w); ov.w = __fadd_rn(xv.w, d3); lacc += (double)__fmul_rn(d3, d3);
            *(float4*)(ob + (long)c * THW + col) = ov;
        }
    }
    #pragma unroll
    for (int m = 1; m < 64; m <<= 1) lacc += __shfl_xor(lacc, m, 64);
    if (lane == 0) wsum[w] = lacc;
    __syncthreads();
    if (tid == 0) {
        double s = 0.0;
        #pragma unroll
        for (int i = 0; i < 8; ++i) s += wsum[i];
        atomicAdd(lossws, s);
    }
}

extern "C" __global__ void vq_finalize(const double* __restrict__ lossws,
                                       float* __restrict__ out) {
    if (threadIdx.x == 0) {
        float m = (float)(lossws[0] / (double)QOUT_N);
        out[LOSSOFF] = __fadd_rn(m, __fmul_rn(0.025f, m));
    }
}

extern "C" void kernel_launch(void* const* d_in, const int* in_sizes, int n_in,
                              void* d_out, int out_size, void* d_ws, size_t ws_size,
                              hipStream_t stream) {
    const float* x   = (const float*)d_in[0];
    const float* emb = (const float*)d_in[1];
    float* out = (float*)d_out;
    double* loss_ws = (double*)d_ws;
    float* ee_ws = (float*)((char*)d_ws + 256);
    unsigned short* ehi_ws  = (unsigned short*)((char*)d_ws + 4096);
    unsigned short* emid_ws = (unsigned short*)((char*)d_ws + 69632);

    hipMemsetAsync(d_ws, 0, sizeof(double), stream);
    hipLaunchKernelGGL(vq_prep, dim3(1), dim3(KCODES), 0, stream, emb, ee_ws, ehi_ws, emid_ws);

    dim3 grid(NPOS / MPOS);   // 2048
    dim3 block(NTHR);
    size_t shmem = 152712;
    hipLaunchKernelGGL(vq_main, grid, block, shmem, stream,
                       x, emb, out, loss_ws, ee_ws, ehi_ws, emid_ws);
    hipLaunchKernelGGL(vq_finalize, dim3(1), dim3(1), 0, stream,
                       (const double*)loss_ws, out);
}